// Round 13
// baseline (124.836 us; speedup 1.0000x reference)
//
#include <hip/hip_runtime.h>

#define CHN 512
#define CKD 64
#define NPOS 4096
#define MPOS 1024

typedef __attribute__((ext_vector_type(8))) short bf16x8;
typedef __attribute__((ext_vector_type(4))) float f32x4;
typedef __attribute__((ext_vector_type(8))) unsigned short u16x8;

// workspace offsets (float units)
static constexpr size_t OFF_O   = 0;          // bf16 o [16][4096][64] (n-major, ck-minor)
static constexpr size_t OFF_THT = 4194304;    // bf16 thetaT [16][4096][64]
static constexpr size_t OFF_PHT = 6291456;    // bf16 phiT   [16][1024][64]
static constexpr size_t OFF_GB  = 6815744;    // bf16 g      [16][64][1024]
static constexpr size_t OFF_WBF = 7340032;    // bf16 W[3][64][512] (k-minor, natural)
static constexpr size_t OFF_WOB = 7389184;    // bf16 Wo [512][64] (k-minor, natural)

__device__ __forceinline__ unsigned short f2bf(float f) {
  union { float f; unsigned int u; } v; v.f = f;
  unsigned int r = v.u + 0x7FFFu + ((v.u >> 16) & 1u);
  return (unsigned short)(r >> 16);
}

__device__ __forceinline__ void gl2lds16(const void* g, void* l) {
  __builtin_amdgcn_global_load_lds(
      (const __attribute__((address_space(1))) unsigned int*)g,
      (__attribute__((address_space(3))) unsigned int*)l, 16, 0, 0);
}

// ---------------------------------------------------------------------------
// K0: weight prep. (unchanged)
// ---------------------------------------------------------------------------
__global__ __launch_bounds__(256) void prep_w_kernel(
    const float* __restrict__ Wt, const float* __restrict__ Wp,
    const float* __restrict__ Wg, const float* __restrict__ Wo,
    unsigned short* __restrict__ wbf, unsigned short* __restrict__ wobf)
{
  int id = blockIdx.x * 256 + threadIdx.x;   // 0..131071
  if (id < 98304) {
    int mat = id >> 15, r = id & 32767;
    const float* W = (mat == 0) ? Wt : (mat == 1) ? Wp : Wg;
    wbf[id] = f2bf(W[r]);
  } else {
    int j = id - 98304;                      // 0..32767
    wobf[j] = f2bf(Wo[j]);
  }
}

// ---------------------------------------------------------------------------
// K1: FUSED transpose + qkv GEMM via MFMA, T14 async-STAGE split. (unchanged)
// ---------------------------------------------------------------------------
__global__ __launch_bounds__(256) void qkv_fused_kernel(
    const float* __restrict__ x,             // [b][512][4096] fp32
    const unsigned short* __restrict__ wbf,  // [3][64][512]
    unsigned short* __restrict__ thT, unsigned short* __restrict__ phT,
    unsigned short* __restrict__ gbf)
{
  __shared__ unsigned short sXb[64 * 132];   // [c][n] bf16, +4 pad
  __shared__ unsigned short sW[3 * 64 * 64]; // [mat][ck][c] rows 128B, swizzled

  const int bx = blockIdx.x;
  const int b  = blockIdx.y;
  const int t  = threadIdx.x;
  const int w   = t >> 6;
  const int l   = t & 63;
  const int l16 = l & 15;
  const int lhi = l >> 4;
  const int n0  = bx * 128;

  const float* xb = x + (size_t)b * CHN * NPOS + n0;
  const int xrow = t >> 5;                   // 0..7 base row
  const int xcol4 = t & 31;

  f32x4 acc[3][2][4];
#pragma unroll
  for (int m = 0; m < 3; ++m)
#pragma unroll
    for (int nf = 0; nf < 2; ++nf)
#pragma unroll
      for (int ckf = 0; ckf < 4; ++ckf) acc[m][nf][ckf] = (f32x4){0.f, 0.f, 0.f, 0.f};

  // T14 prologue: prefetch chunk 0 of x into registers
  float4 xR[8];
#pragma unroll
  for (int i = 0; i < 8; ++i)
    xR[i] = *(const float4*)(xb + (size_t)(i * 8 + xrow) * NPOS + xcol4 * 4);

  for (int c0 = 0; c0 < CHN; c0 += 64) {
    if (c0) __syncthreads();                 // previous chunk readers done
    // issue W async loads first (latency hides under x cvt/write below)
#pragma unroll
    for (int mi = 0; mi < 6; ++mi) {
      int mat = mi >> 1;
      int row = ((mi & 1) * 4 + w) * 8 + (l >> 3);   // 0..63
      int sbyte = (l & 7) * 16;
      const char* g = (const char*)wbf +
          ((((size_t)mat * 64 + row) * CHN + c0) << 1) + (sbyte ^ ((row & 7) << 4));
      gl2lds16(g, (char*)sW + mi * 4096 + w * 1024);
    }
    // write x chunk from prefetched regs (cvt to bf16)
#pragma unroll
    for (int i = 0; i < 8; ++i) {
      ushort4 u;
      u.x = f2bf(xR[i].x); u.y = f2bf(xR[i].y);
      u.z = f2bf(xR[i].z); u.w = f2bf(xR[i].w);
      *(ushort4*)&sXb[(i * 8 + xrow) * 132 + xcol4 * 4] = u;
    }
    __syncthreads();                         // drains W; x writes visible

    // T14: issue next chunk's x loads (consumed at next iter's write phase)
    if (c0 + 64 < CHN) {
#pragma unroll
      for (int i = 0; i < 8; ++i)
        xR[i] = *(const float4*)(xb + (size_t)(c0 + 64 + i * 8 + xrow) * NPOS + xcol4 * 4);
    }

#pragma unroll
    for (int ks = 0; ks < 2; ++ks) {
      const int cu = ks * 32 + lhi * 8;      // channel base of this k-slice
      bf16x8 a[2];
#pragma unroll
      for (int nf = 0; nf < 2; ++nf) {
        const int rn = 16 * w + 64 * nf + l16;
        bf16x8 av;
#pragma unroll
        for (int e = 0; e < 8; ++e)
          av[e] = (short)sXb[(cu + e) * 132 + rn];
        a[nf] = av;
      }
#pragma unroll
      for (int m = 0; m < 3; ++m)
#pragma unroll
        for (int ckf = 0; ckf < 4; ++ckf) {
          int rw = ckf * 16 + l16;
          bf16x8 bb = *(const bf16x8*)&sW[m * 4096 + rw * 64 + (cu ^ ((rw & 7) * 8))];
          acc[m][0][ckf] = __builtin_amdgcn_mfma_f32_16x16x32_bf16(a[0], bb, acc[m][0][ckf], 0, 0, 0);
          acc[m][1][ckf] = __builtin_amdgcn_mfma_f32_16x16x32_bf16(a[1], bb, acc[m][1][ckf], 0, 0, 0);
        }
    }
  }

  // epilogue: theta full-res [n][ck] bf16
  unsigned short* th = thT + (size_t)b * NPOS * 64;
#pragma unroll
  for (int nf = 0; nf < 2; ++nf)
#pragma unroll
    for (int r = 0; r < 4; ++r) {
      int n = n0 + 16 * w + 64 * nf + lhi * 4 + r;
#pragma unroll
      for (int ckf = 0; ckf < 4; ++ckf)
        th[(size_t)n * 64 + ckf * 16 + l16] = f2bf(acc[0][nf][ckf][r]);
    }

  // phi/g: 2x2 maxpool in-register. pooled row = bx, col j = 8w + lhi*2 + pr.
  unsigned short* ph = phT + (size_t)b * MPOS * 64;
  unsigned short* gb = gbf + (size_t)b * CKD * MPOS;
#pragma unroll
  for (int pr = 0; pr < 2; ++pr) {
    int mcol = bx * 32 + 8 * w + lhi * 2 + pr;
#pragma unroll
    for (int ckf = 0; ckf < 4; ++ckf) {
      int ck = ckf * 16 + l16;
      float vp = fmaxf(fmaxf(acc[1][0][ckf][2 * pr], acc[1][0][ckf][2 * pr + 1]),
                       fmaxf(acc[1][1][ckf][2 * pr], acc[1][1][ckf][2 * pr + 1]));
      float vg = fmaxf(fmaxf(acc[2][0][ckf][2 * pr], acc[2][0][ckf][2 * pr + 1]),
                       fmaxf(acc[2][1][ckf][2 * pr], acc[2][1][ckf][2 * pr + 1]));
      ph[(size_t)mcol * 64 + ck] = f2bf(vp);
      gb[(size_t)ck * MPOS + mcol] = f2bf(vg);
    }
  }
}

// ---------------------------------------------------------------------------
// K2: fused flash attention, QBLK=128, T14 reg-staged phi/g, no-max softmax,
// ones-MFMA row-sum. (unchanged from round 11)
// ---------------------------------------------------------------------------
__global__ __launch_bounds__(256) void attn_kernel(
    const unsigned short* __restrict__ thT,  // [b][4096][64]
    const unsigned short* __restrict__ phT,  // [b][1024][64]
    const unsigned short* __restrict__ gbf,  // [b][64][1024]
    unsigned short* __restrict__ obf)        // [b][4096][64] bf16
{
  __shared__ unsigned short sTh[128 * 64];   // [q][ck] swizzled rows 128B
  __shared__ unsigned short sP [128 * 64];   // [q][m]  swizzled
  __shared__ unsigned short sPhi[64 * 64];   // [m][ck] swizzled
  __shared__ unsigned short sG [64 * 64];    // [ck][m] swizzled

  const int qt = blockIdx.x;                 // 32 tiles of 128 q
  const int b  = blockIdx.y;
  const int t  = threadIdx.x;
  const int w   = t >> 6;
  const int l   = t & 63;
  const int l16 = l & 15;
  const int lhi = l >> 4;

  // stage theta tile: 128 rows x 128B = 1024 chunks (async; drains at barrier)
  {
    const char* srcb = (const char*)(thT + ((size_t)b * NPOS + (size_t)qt * 128) * 64);
#pragma unroll
    for (int i = 0; i < 4; ++i) {
      int cidx = i * 256 + t;
      int row = cidx >> 3, sub = cidx & 7;
      gl2lds16(srcb + row * 128 + ((sub * 16) ^ ((row & 7) << 4)),
               (char*)sTh + (i * 256 + w * 64) * 16);
    }
  }

  f32x4 oacc[2][4];
  f32x4 lacc[2];                             // row-sum accumulators (ones-MFMA)
#pragma unroll
  for (int qf = 0; qf < 2; ++qf) {
    lacc[qf] = (f32x4){0.f, 0.f, 0.f, 0.f};
#pragma unroll
    for (int i = 0; i < 4; ++i) oacc[qf][i] = (f32x4){0.f, 0.f, 0.f, 0.f};
  }

  bf16x8 ones;
#pragma unroll
  for (int e = 0; e < 8; ++e) ones[e] = (short)0x3F80;   // bf16 1.0

  const unsigned short* phb = phT + (size_t)b * MPOS * 64;
  const unsigned short* gb  = gbf + (size_t)b * CKD * MPOS;

  // T14 prologue: prefetch phi/g tiles for mt=0 into registers
  const int srow = t >> 3;                   // 0..31 base row (i adds 32)
  const int ssub = t & 7;
  u16x8 phR[2], gR[2];
#pragma unroll
  for (int i = 0; i < 2; ++i) {
    int row = i * 32 + srow;
    phR[i] = *(const u16x8*)(phb + (size_t)row * 64 + ssub * 8);
    gR[i]  = *(const u16x8*)(gb + (size_t)row * MPOS + ssub * 8);
  }

  for (int mt = 0; mt < 16; ++mt) {
    __syncthreads();                         // prev-iter readers done (+theta drain at mt=0)
    // write phi/g tiles from prefetched regs (swizzled)
#pragma unroll
    for (int i = 0; i < 2; ++i) {
      int row = i * 32 + srow;
      int off = row * 64 + ((ssub * 8) ^ ((row & 7) * 8));
      *(u16x8*)&sPhi[off] = phR[i];
      *(u16x8*)&sG[off]   = gR[i];
    }
    __syncthreads();                         // writes visible

    // T14: issue next-iter loads (vmcnt-waited at next iter's write phase)
    if (mt + 1 < 16) {
#pragma unroll
      for (int i = 0; i < 2; ++i) {
        int row = i * 32 + srow;
        phR[i] = *(const u16x8*)(phb + (size_t)((mt + 1) * 64 + row) * 64 + ssub * 8);
        gR[i]  = *(const u16x8*)(gb + (size_t)row * MPOS + (mt + 1) * 64 + ssub * 8);
      }
    }

    // QK^T: S[32q x 64m] per wave (2 q-frags)
    f32x4 sacc[2][4];
#pragma unroll
    for (int qf = 0; qf < 2; ++qf)
#pragma unroll
      for (int mf = 0; mf < 4; ++mf) sacc[qf][mf] = (f32x4){0.f, 0.f, 0.f, 0.f};
#pragma unroll
    for (int qf = 0; qf < 2; ++qf)
#pragma unroll
      for (int ks = 0; ks < 2; ++ks) {
        const int q  = 32 * w + 16 * qf + l16;
        const int ob = lhi * 8 + 32 * ks;
        bf16x8 a = *(const bf16x8*)&sTh[q * 64 + (ob ^ ((q & 7) * 8))];
#pragma unroll
        for (int mf = 0; mf < 4; ++mf) {
          const int m = l16 + 16 * mf;
          bf16x8 bb = *(const bf16x8*)&sPhi[m * 64 + (ob ^ ((m & 7) * 8))];
          sacc[qf][mf] = __builtin_amdgcn_mfma_f32_16x16x32_bf16(a, bb, sacc[qf][mf], 0, 0, 0);
        }
      }

    // softmax numerator: p = expf(s) (no max subtraction), write P to LDS
#pragma unroll
    for (int qf = 0; qf < 2; ++qf)
#pragma unroll
      for (int r = 0; r < 4; ++r) {
        const int qq = 32 * w + 16 * qf + lhi * 4 + r;
        const int swz = (qq & 7) * 8;
#pragma unroll
        for (int mf = 0; mf < 4; ++mf) {
          const int m = l16 + 16 * mf;
          sP[qq * 64 + ((m & 0x38) ^ swz) + (m & 7)] = f2bf(__expf(sacc[qf][mf][r]));
        }
      }

    // PV: O += P * g^T; row-sum l += P * 1 (ones-MFMA, same A-frags)
#pragma unroll
    for (int qf = 0; qf < 2; ++qf)
#pragma unroll
      for (int ks = 0; ks < 2; ++ks) {
        const int q  = 32 * w + 16 * qf + l16;
        const int ob = lhi * 8 + 32 * ks;
        bf16x8 a = *(const bf16x8*)&sP[q * 64 + (ob ^ ((q & 7) * 8))];
        lacc[qf] = __builtin_amdgcn_mfma_f32_16x16x32_bf16(a, ones, lacc[qf], 0, 0, 0);
#pragma unroll
        for (int ckf = 0; ckf < 4; ++ckf) {
          const int ck = l16 + 16 * ckf;
          bf16x8 bb = *(const bf16x8*)&sG[ck * 64 + (ob ^ ((ck & 7) * 8))];
          oacc[qf][ckf] = __builtin_amdgcn_mfma_f32_16x16x32_bf16(a, bb, oacc[qf][ckf], 0, 0, 0);
        }
      }
  }

  // epilogue: normalize, write o bf16 [n][ck]
  unsigned short* ob = obf + (size_t)b * NPOS * 64;
#pragma unroll
  for (int qf = 0; qf < 2; ++qf) {
    float inv[4];
#pragma unroll
    for (int r = 0; r < 4; ++r) inv[r] = 1.0f / lacc[qf][r];
#pragma unroll
    for (int r = 0; r < 4; ++r) {
      int n = qt * 128 + 32 * w + 16 * qf + lhi * 4 + r;
#pragma unroll
      for (int ckf = 0; ckf < 4; ++ckf)
        ob[(size_t)n * 64 + ckf * 16 + l16] = f2bf(oacc[qf][ckf][r] * inv[r]);
    }
  }
}

// ---------------------------------------------------------------------------
// K3: out = x + gamma * (Wo @ o) via bf16 MFMA.
// out stores NON-TEMPORAL via clang ext-vector f32x4 (float4 HIP class is
// not a valid nontemporal operand — round-12 compile fix).
// ---------------------------------------------------------------------------
__global__ __launch_bounds__(256) void outconv_mfma_kernel(
    const float* __restrict__ x,
    const unsigned short* __restrict__ wobf,  // [512][64] bf16 k-minor
    const unsigned short* __restrict__ obf,   // [b][4096][64] bf16
    const float* __restrict__ gamma_p, float* __restrict__ outp)
{
  __shared__ unsigned short sO[256 * 64];     // [n][ck] rows 128B, swizzled
  __shared__ unsigned short sWo[64 * 64];     // [co][ck] rows 128B, swizzled

  const int nt = blockIdx.x;                  // 16 tiles of 256 n
  const int ct = blockIdx.y;                  // 8 tiles of 64 co
  const int b  = blockIdx.z;
  const int t  = threadIdx.x;
  const int w   = t >> 6;
  const int l   = t & 63;
  const int l16 = l & 15;
  const int lhi = l >> 4;

#pragma unroll
  for (int i = 0; i < 8; ++i) {
    int cidx = i * 256 + t;
    int row = cidx >> 3, sub = cidx & 7;
    const char* g = (const char*)obf +
        ((((size_t)b * NPOS + nt * 256 + row) * 64) << 1) + ((sub * 16) ^ ((row & 7) << 4));
    gl2lds16(g, (char*)sO + (i * 256 + w * 64) * 16);
  }
#pragma unroll
  for (int i = 0; i < 2; ++i) {
    int cidx = i * 256 + t;
    int row = cidx >> 3, sub = cidx & 7;      // row 0..63
    const char* g = (const char*)wobf +
        ((((size_t)(ct * 64 + row)) * 64) << 1) + ((sub * 16) ^ ((row & 7) << 4));
    gl2lds16(g, (char*)sWo + (i * 256 + w * 64) * 16);
  }

  const float gv = *gamma_p;
  float4 xv[4][4];
#pragma unroll
  for (int nf = 0; nf < 4; ++nf) {
    const int n = nt * 256 + w * 64 + nf * 16 + lhi * 4;
#pragma unroll
    for (int cf = 0; cf < 4; ++cf) {
      const int co = ct * 64 + cf * 16 + l16;
      xv[nf][cf] = *(const float4*)(x + ((size_t)b * CHN + co) * NPOS + n);
    }
  }
  __syncthreads();

  f32x4 acc[4][4];
#pragma unroll
  for (int nf = 0; nf < 4; ++nf)
#pragma unroll
    for (int cf = 0; cf < 4; ++cf) acc[nf][cf] = (f32x4){0.f, 0.f, 0.f, 0.f};

#pragma unroll
  for (int ks = 0; ks < 2; ++ks) {
    const int cu = ks * 32 + lhi * 8;
    bf16x8 a[4];
#pragma unroll
    for (int nf = 0; nf < 4; ++nf) {
      int rn = w * 64 + nf * 16 + l16;
      a[nf] = *(const bf16x8*)&sO[rn * 64 + (cu ^ ((rn & 7) * 8))];
    }
#pragma unroll
    for (int cf = 0; cf < 4; ++cf) {
      int rw = cf * 16 + l16;
      bf16x8 bb = *(const bf16x8*)&sWo[rw * 64 + (cu ^ ((rw & 7) * 8))];
#pragma unroll
      for (int nf = 0; nf < 4; ++nf)
        acc[nf][cf] = __builtin_amdgcn_mfma_f32_16x16x32_bf16(a[nf], bb, acc[nf][cf], 0, 0, 0);
    }
  }

#pragma unroll
  for (int nf = 0; nf < 4; ++nf) {
    const int n = nt * 256 + w * 64 + nf * 16 + lhi * 4;
#pragma unroll
    for (int cf = 0; cf < 4; ++cf) {
      const int co = ct * 64 + cf * 16 + l16;
      const size_t off = ((size_t)b * CHN + co) * NPOS + n;
      f32x4 rr;
      rr[0] = fmaf(gv, acc[nf][cf][0], xv[nf][cf].x);
      rr[1] = fmaf(gv, acc[nf][cf][1], xv[nf][cf].y);
      rr[2] = fmaf(gv, acc[nf][cf][2], xv[nf][cf].z);
      rr[3] = fmaf(gv, acc[nf][cf][3], xv[nf][cf].w);
      __builtin_nontemporal_store(rr, (f32x4*)(outp + off));   // nt: don't evict x
    }
  }
}

// ---------------------------------------------------------------------------
extern "C" void kernel_launch(void* const* d_in, const int* in_sizes, int n_in,
                              void* d_out, int out_size, void* d_ws, size_t ws_size,
                              hipStream_t stream)
{
  const float* x     = (const float*)d_in[0];
  const float* Wt    = (const float*)d_in[1];
  const float* Wp    = (const float*)d_in[2];
  const float* Wg    = (const float*)d_in[3];
  const float* Wo    = (const float*)d_in[4];
  const float* gamma = (const float*)d_in[5];
  float* out = (float*)d_out;
  float* ws  = (float*)d_ws;

  unsigned short* obf = (unsigned short*)(ws + OFF_O);
  unsigned short* thT = (unsigned short*)(ws + OFF_THT);
  unsigned short* phT = (unsigned short*)(ws + OFF_PHT);
  unsigned short* gbf = (unsigned short*)(ws + OFF_GB);
  unsigned short* wbf = (unsigned short*)(ws + OFF_WBF);
  unsigned short* wob = (unsigned short*)(ws + OFF_WOB);

  prep_w_kernel<<<dim3(512), 256, 0, stream>>>(Wt, Wp, Wg, Wo, wbf, wob);
  qkv_fused_kernel<<<dim3(32, 16), 256, 0, stream>>>(x, wbf, thT, phT, gbf);
  attn_kernel<<<dim3(32, 16), 256, 0, stream>>>(thT, phT, gbf, obf);
  outconv_mfma_kernel<<<dim3(16, 8, 16), 256, 0, stream>>>(x, wob, obf, gamma, out);
}

// Round 14
// 121.619 us; speedup vs baseline: 1.0265x; 1.0265x over previous
//
#include <hip/hip_runtime.h>

#define CHN 512
#define CKD 64
#define NPOS 4096
#define MPOS 1024

typedef __attribute__((ext_vector_type(8))) short bf16x8;
typedef __attribute__((ext_vector_type(4))) float f32x4;
typedef __attribute__((ext_vector_type(8))) unsigned short u16x8;

// workspace offsets (float units)
static constexpr size_t OFF_O   = 0;          // bf16 o [16][4096][64] (n-major, ck-minor)
static constexpr size_t OFF_THT = 4194304;    // bf16 thetaT [16][4096][64]
static constexpr size_t OFF_PHT = 6291456;    // bf16 phiT   [16][1024][64]
static constexpr size_t OFF_GB  = 6815744;    // bf16 g      [16][64][1024]
static constexpr size_t OFF_WBF = 7340032;    // bf16 W[3][64][512] (k-minor, natural)
static constexpr size_t OFF_WOB = 7389184;    // bf16 Wo [512][64] (k-minor, natural)

__device__ __forceinline__ unsigned short f2bf(float f) {
  union { float f; unsigned int u; } v; v.f = f;
  unsigned int r = v.u + 0x7FFFu + ((v.u >> 16) & 1u);
  return (unsigned short)(r >> 16);
}

__device__ __forceinline__ void gl2lds16(const void* g, void* l) {
  __builtin_amdgcn_global_load_lds(
      (const __attribute__((address_space(1))) unsigned int*)g,
      (__attribute__((address_space(3))) unsigned int*)l, 16, 0, 0);
}

// ---------------------------------------------------------------------------
// K0: weight prep. (unchanged)
// ---------------------------------------------------------------------------
__global__ __launch_bounds__(256) void prep_w_kernel(
    const float* __restrict__ Wt, const float* __restrict__ Wp,
    const float* __restrict__ Wg, const float* __restrict__ Wo,
    unsigned short* __restrict__ wbf, unsigned short* __restrict__ wobf)
{
  int id = blockIdx.x * 256 + threadIdx.x;   // 0..131071
  if (id < 98304) {
    int mat = id >> 15, r = id & 32767;
    const float* W = (mat == 0) ? Wt : (mat == 1) ? Wp : Wg;
    wbf[id] = f2bf(W[r]);
  } else {
    int j = id - 98304;                      // 0..32767
    wobf[j] = f2bf(Wo[j]);
  }
}

// ---------------------------------------------------------------------------
// K1: FUSED transpose + qkv GEMM via MFMA.
// NEW (r14): no gl2lds in the loop — W is reg-staged like x, so NO barrier
// forces a vmcnt(0) drain of the prefetch streams; x prefetch deepened to
// 2 chunks (xA/xB named buffers, loop unrolled x2). LDS content/layout and
// MFMA indexing byte-identical to r13.
// ---------------------------------------------------------------------------
__global__ __launch_bounds__(256) void qkv_fused_kernel(
    const float* __restrict__ x,             // [b][512][4096] fp32
    const unsigned short* __restrict__ wbf,  // [3][64][512]
    unsigned short* __restrict__ thT, unsigned short* __restrict__ phT,
    unsigned short* __restrict__ gbf)
{
  __shared__ unsigned short sXb[64 * 132];   // [c][n] bf16, +4 pad
  __shared__ unsigned short sW[3 * 64 * 64]; // [mat][ck][c] rows 128B, swizzled

  const int bx = blockIdx.x;
  const int b  = blockIdx.y;
  const int t  = threadIdx.x;
  const int w   = t >> 6;
  const int l   = t & 63;
  const int l16 = l & 15;
  const int lhi = l >> 4;
  const int n0  = bx * 128;

  const float* xb = x + (size_t)b * CHN * NPOS + n0;
  const int xrow = t >> 5;                   // 0..7 base row
  const int xcol4 = t & 31;

  f32x4 acc[3][2][4];
#pragma unroll
  for (int m = 0; m < 3; ++m)
#pragma unroll
    for (int nf = 0; nf < 2; ++nf)
#pragma unroll
      for (int ckf = 0; ckf < 4; ++ckf) acc[m][nf][ckf] = (f32x4){0.f, 0.f, 0.f, 0.f};

#define LOADX(buf, c0)                                                         \
  _Pragma("unroll")                                                            \
  for (int i = 0; i < 8; ++i)                                                  \
    buf[i] = *(const float4*)(xb + (size_t)((c0) + i * 8 + xrow) * NPOS + xcol4 * 4);

#define WRITEX(buf)                                                            \
  _Pragma("unroll")                                                            \
  for (int i = 0; i < 8; ++i) {                                                \
    ushort4 u;                                                                 \
    u.x = f2bf(buf[i].x); u.y = f2bf(buf[i].y);                                \
    u.z = f2bf(buf[i].z); u.w = f2bf(buf[i].w);                                \
    *(ushort4*)&sXb[(i * 8 + xrow) * 132 + xcol4 * 4] = u;                     \
  }

#define LOADW(wR, c0)                                                          \
  _Pragma("unroll")                                                            \
  for (int mi = 0; mi < 6; ++mi) {                                             \
    int row = ((mi & 1) * 4 + w) * 8 + (l >> 3);                               \
    int sbyte = (l & 7) * 16;                                                  \
    int mat = mi >> 1;                                                         \
    wR[mi] = *(const u16x8*)((const char*)wbf +                                \
        ((((size_t)mat * 64 + row) * CHN + (c0)) << 1) + (sbyte ^ ((row & 7) << 4))); \
  }

#define WRITEW(wR)                                                             \
  _Pragma("unroll")                                                            \
  for (int mi = 0; mi < 6; ++mi)                                               \
    *(u16x8*)((char*)sW + mi * 4096 + w * 1024 + l * 16) = wR[mi];

#define MFMA_PHASE()                                                           \
  _Pragma("unroll")                                                            \
  for (int ks = 0; ks < 2; ++ks) {                                             \
    const int cu = ks * 32 + lhi * 8;                                          \
    bf16x8 a[2];                                                               \
    _Pragma("unroll")                                                          \
    for (int nf = 0; nf < 2; ++nf) {                                           \
      const int rn = 16 * w + 64 * nf + l16;                                   \
      bf16x8 av;                                                               \
      _Pragma("unroll")                                                        \
      for (int e = 0; e < 8; ++e)                                              \
        av[e] = (short)sXb[(cu + e) * 132 + rn];                               \
      a[nf] = av;                                                              \
    }                                                                          \
    _Pragma("unroll")                                                          \
    for (int m = 0; m < 3; ++m)                                                \
      _Pragma("unroll")                                                        \
      for (int ckf = 0; ckf < 4; ++ckf) {                                      \
        int rw = ckf * 16 + l16;                                               \
        bf16x8 bb = *(const bf16x8*)&sW[m * 4096 + rw * 64 + (cu ^ ((rw & 7) * 8))]; \
        acc[m][0][ckf] = __builtin_amdgcn_mfma_f32_16x16x32_bf16(a[0], bb, acc[m][0][ckf], 0, 0, 0); \
        acc[m][1][ckf] = __builtin_amdgcn_mfma_f32_16x16x32_bf16(a[1], bb, acc[m][1][ckf], 0, 0, 0); \
      }                                                                        \
  }

  // prologue: x 2-deep, W 1-deep
  float4 xA[8], xB[8];
  u16x8 wR[6];
  LOADX(xA, 0);
  LOADX(xB, 64);
  LOADW(wR, 0);

#pragma unroll
  for (int cc = 0; cc < 4; ++cc) {
    const int c0 = cc * 128;
    // even sub-iter: consume xA (chunk c0), W (chunk c0)
    if (c0) __syncthreads();                 // prev readers done
    WRITEX(xA);                              // waits xA loads (counted vmcnt)
    WRITEW(wR);
    __syncthreads();                         // lgkmcnt drain only (no gl2lds)
    if (c0 + 128 < CHN) LOADX(xA, c0 + 128); // refill 2-deep
    LOADW(wR, c0 + 64);                      // refill W 1-deep (c0+64 <= 448)
    MFMA_PHASE();

    // odd sub-iter: consume xB (chunk c0+64), W (chunk c0+64)
    __syncthreads();
    WRITEX(xB);
    WRITEW(wR);
    __syncthreads();
    if (c0 + 192 < CHN) LOADX(xB, c0 + 192);
    if (c0 + 128 < CHN) LOADW(wR, c0 + 128);
    MFMA_PHASE();
  }

#undef LOADX
#undef WRITEX
#undef LOADW
#undef WRITEW
#undef MFMA_PHASE

  // epilogue: theta full-res [n][ck] bf16
  unsigned short* th = thT + (size_t)b * NPOS * 64;
#pragma unroll
  for (int nf = 0; nf < 2; ++nf)
#pragma unroll
    for (int r = 0; r < 4; ++r) {
      int n = n0 + 16 * w + 64 * nf + lhi * 4 + r;
#pragma unroll
      for (int ckf = 0; ckf < 4; ++ckf)
        th[(size_t)n * 64 + ckf * 16 + l16] = f2bf(acc[0][nf][ckf][r]);
    }

  // phi/g: 2x2 maxpool in-register. pooled row = bx, col j = 8w + lhi*2 + pr.
  unsigned short* ph = phT + (size_t)b * MPOS * 64;
  unsigned short* gb = gbf + (size_t)b * CKD * MPOS;
#pragma unroll
  for (int pr = 0; pr < 2; ++pr) {
    int mcol = bx * 32 + 8 * w + lhi * 2 + pr;
#pragma unroll
    for (int ckf = 0; ckf < 4; ++ckf) {
      int ck = ckf * 16 + l16;
      float vp = fmaxf(fmaxf(acc[1][0][ckf][2 * pr], acc[1][0][ckf][2 * pr + 1]),
                       fmaxf(acc[1][1][ckf][2 * pr], acc[1][1][ckf][2 * pr + 1]));
      float vg = fmaxf(fmaxf(acc[2][0][ckf][2 * pr], acc[2][0][ckf][2 * pr + 1]),
                       fmaxf(acc[2][1][ckf][2 * pr], acc[2][1][ckf][2 * pr + 1]));
      ph[(size_t)mcol * 64 + ck] = f2bf(vp);
      gb[(size_t)ck * MPOS + mcol] = f2bf(vg);
    }
  }
}

// ---------------------------------------------------------------------------
// K2: fused flash attention, QBLK=128, T14 reg-staged phi/g, no-max softmax,
// ones-MFMA row-sum. (unchanged from round 11)
// ---------------------------------------------------------------------------
__global__ __launch_bounds__(256) void attn_kernel(
    const unsigned short* __restrict__ thT,  // [b][4096][64]
    const unsigned short* __restrict__ phT,  // [b][1024][64]
    const unsigned short* __restrict__ gbf,  // [b][64][1024]
    unsigned short* __restrict__ obf)        // [b][4096][64] bf16
{
  __shared__ unsigned short sTh[128 * 64];   // [q][ck] swizzled rows 128B
  __shared__ unsigned short sP [128 * 64];   // [q][m]  swizzled
  __shared__ unsigned short sPhi[64 * 64];   // [m][ck] swizzled
  __shared__ unsigned short sG [64 * 64];    // [ck][m] swizzled

  const int qt = blockIdx.x;                 // 32 tiles of 128 q
  const int b  = blockIdx.y;
  const int t  = threadIdx.x;
  const int w   = t >> 6;
  const int l   = t & 63;
  const int l16 = l & 15;
  const int lhi = l >> 4;

  // stage theta tile: 128 rows x 128B = 1024 chunks (async; drains at barrier)
  {
    const char* srcb = (const char*)(thT + ((size_t)b * NPOS + (size_t)qt * 128) * 64);
#pragma unroll
    for (int i = 0; i < 4; ++i) {
      int cidx = i * 256 + t;
      int row = cidx >> 3, sub = cidx & 7;
      gl2lds16(srcb + row * 128 + ((sub * 16) ^ ((row & 7) << 4)),
               (char*)sTh + (i * 256 + w * 64) * 16);
    }
  }

  f32x4 oacc[2][4];
  f32x4 lacc[2];                             // row-sum accumulators (ones-MFMA)
#pragma unroll
  for (int qf = 0; qf < 2; ++qf) {
    lacc[qf] = (f32x4){0.f, 0.f, 0.f, 0.f};
#pragma unroll
    for (int i = 0; i < 4; ++i) oacc[qf][i] = (f32x4){0.f, 0.f, 0.f, 0.f};
  }

  bf16x8 ones;
#pragma unroll
  for (int e = 0; e < 8; ++e) ones[e] = (short)0x3F80;   // bf16 1.0

  const unsigned short* phb = phT + (size_t)b * MPOS * 64;
  const unsigned short* gb  = gbf + (size_t)b * CKD * MPOS;

  // T14 prologue: prefetch phi/g tiles for mt=0 into registers
  const int srow = t >> 3;                   // 0..31 base row (i adds 32)
  const int ssub = t & 7;
  u16x8 phR[2], gR[2];
#pragma unroll
  for (int i = 0; i < 2; ++i) {
    int row = i * 32 + srow;
    phR[i] = *(const u16x8*)(phb + (size_t)row * 64 + ssub * 8);
    gR[i]  = *(const u16x8*)(gb + (size_t)row * MPOS + ssub * 8);
  }

  for (int mt = 0; mt < 16; ++mt) {
    __syncthreads();                         // prev-iter readers done (+theta drain at mt=0)
    // write phi/g tiles from prefetched regs (swizzled)
#pragma unroll
    for (int i = 0; i < 2; ++i) {
      int row = i * 32 + srow;
      int off = row * 64 + ((ssub * 8) ^ ((row & 7) * 8));
      *(u16x8*)&sPhi[off] = phR[i];
      *(u16x8*)&sG[off]   = gR[i];
    }
    __syncthreads();                         // writes visible

    // T14: issue next-iter loads (vmcnt-waited at next iter's write phase)
    if (mt + 1 < 16) {
#pragma unroll
      for (int i = 0; i < 2; ++i) {
        int row = i * 32 + srow;
        phR[i] = *(const u16x8*)(phb + (size_t)((mt + 1) * 64 + row) * 64 + ssub * 8);
        gR[i]  = *(const u16x8*)(gb + (size_t)row * MPOS + (mt + 1) * 64 + ssub * 8);
      }
    }

    // QK^T: S[32q x 64m] per wave (2 q-frags)
    f32x4 sacc[2][4];
#pragma unroll
    for (int qf = 0; qf < 2; ++qf)
#pragma unroll
      for (int mf = 0; mf < 4; ++mf) sacc[qf][mf] = (f32x4){0.f, 0.f, 0.f, 0.f};
#pragma unroll
    for (int qf = 0; qf < 2; ++qf)
#pragma unroll
      for (int ks = 0; ks < 2; ++ks) {
        const int q  = 32 * w + 16 * qf + l16;
        const int ob = lhi * 8 + 32 * ks;
        bf16x8 a = *(const bf16x8*)&sTh[q * 64 + (ob ^ ((q & 7) * 8))];
#pragma unroll
        for (int mf = 0; mf < 4; ++mf) {
          const int m = l16 + 16 * mf;
          bf16x8 bb = *(const bf16x8*)&sPhi[m * 64 + (ob ^ ((m & 7) * 8))];
          sacc[qf][mf] = __builtin_amdgcn_mfma_f32_16x16x32_bf16(a, bb, sacc[qf][mf], 0, 0, 0);
        }
      }

    // softmax numerator: p = expf(s) (no max subtraction), write P to LDS
#pragma unroll
    for (int qf = 0; qf < 2; ++qf)
#pragma unroll
      for (int r = 0; r < 4; ++r) {
        const int qq = 32 * w + 16 * qf + lhi * 4 + r;
        const int swz = (qq & 7) * 8;
#pragma unroll
        for (int mf = 0; mf < 4; ++mf) {
          const int m = l16 + 16 * mf;
          sP[qq * 64 + ((m & 0x38) ^ swz) + (m & 7)] = f2bf(__expf(sacc[qf][mf][r]));
        }
      }

    // PV: O += P * g^T; row-sum l += P * 1 (ones-MFMA, same A-frags)
#pragma unroll
    for (int qf = 0; qf < 2; ++qf)
#pragma unroll
      for (int ks = 0; ks < 2; ++ks) {
        const int q  = 32 * w + 16 * qf + l16;
        const int ob = lhi * 8 + 32 * ks;
        bf16x8 a = *(const bf16x8*)&sP[q * 64 + (ob ^ ((q & 7) * 8))];
        lacc[qf] = __builtin_amdgcn_mfma_f32_16x16x32_bf16(a, ones, lacc[qf], 0, 0, 0);
#pragma unroll
        for (int ckf = 0; ckf < 4; ++ckf) {
          const int ck = l16 + 16 * ckf;
          bf16x8 bb = *(const bf16x8*)&sG[ck * 64 + (ob ^ ((ck & 7) * 8))];
          oacc[qf][ckf] = __builtin_amdgcn_mfma_f32_16x16x32_bf16(a, bb, oacc[qf][ckf], 0, 0, 0);
        }
      }
  }

  // epilogue: normalize, write o bf16 [n][ck]
  unsigned short* ob = obf + (size_t)b * NPOS * 64;
#pragma unroll
  for (int qf = 0; qf < 2; ++qf) {
    float inv[4];
#pragma unroll
    for (int r = 0; r < 4; ++r) inv[r] = 1.0f / lacc[qf][r];
#pragma unroll
    for (int r = 0; r < 4; ++r) {
      int n = qt * 128 + 32 * w + 16 * qf + lhi * 4 + r;
#pragma unroll
      for (int ckf = 0; ckf < 4; ++ckf)
        ob[(size_t)n * 64 + ckf * 16 + l16] = f2bf(oacc[qf][ckf][r] * inv[r]);
    }
  }
}

// ---------------------------------------------------------------------------
// K3: out = x + gamma * (Wo @ o) via bf16 MFMA. (unchanged from round 13;
// nt-store kept — neutral but harmless)
// ---------------------------------------------------------------------------
__global__ __launch_bounds__(256) void outconv_mfma_kernel(
    const float* __restrict__ x,
    const unsigned short* __restrict__ wobf,  // [512][64] bf16 k-minor
    const unsigned short* __restrict__ obf,   // [b][4096][64] bf16
    const float* __restrict__ gamma_p, float* __restrict__ outp)
{
  __shared__ unsigned short sO[256 * 64];     // [n][ck] rows 128B, swizzled
  __shared__ unsigned short sWo[64 * 64];     // [co][ck] rows 128B, swizzled

  const int nt = blockIdx.x;                  // 16 tiles of 256 n
  const int ct = blockIdx.y;                  // 8 tiles of 64 co
  const int b  = blockIdx.z;
  const int t  = threadIdx.x;
  const int w   = t >> 6;
  const int l   = t & 63;
  const int l16 = l & 15;
  const int lhi = l >> 4;

#pragma unroll
  for (int i = 0; i < 8; ++i) {
    int cidx = i * 256 + t;
    int row = cidx >> 3, sub = cidx & 7;
    const char* g = (const char*)obf +
        ((((size_t)b * NPOS + nt * 256 + row) * 64) << 1) + ((sub * 16) ^ ((row & 7) << 4));
    gl2lds16(g, (char*)sO + (i * 256 + w * 64) * 16);
  }
#pragma unroll
  for (int i = 0; i < 2; ++i) {
    int cidx = i * 256 + t;
    int row = cidx >> 3, sub = cidx & 7;      // row 0..63
    const char* g = (const char*)wobf +
        ((((size_t)(ct * 64 + row)) * 64) << 1) + ((sub * 16) ^ ((row & 7) << 4));
    gl2lds16(g, (char*)sWo + (i * 256 + w * 64) * 16);
  }

  const float gv = *gamma_p;
  float4 xv[4][4];
#pragma unroll
  for (int nf = 0; nf < 4; ++nf) {
    const int n = nt * 256 + w * 64 + nf * 16 + lhi * 4;
#pragma unroll
    for (int cf = 0; cf < 4; ++cf) {
      const int co = ct * 64 + cf * 16 + l16;
      xv[nf][cf] = *(const float4*)(x + ((size_t)b * CHN + co) * NPOS + n);
    }
  }
  __syncthreads();

  f32x4 acc[4][4];
#pragma unroll
  for (int nf = 0; nf < 4; ++nf)
#pragma unroll
    for (int cf = 0; cf < 4; ++cf) acc[nf][cf] = (f32x4){0.f, 0.f, 0.f, 0.f};

#pragma unroll
  for (int ks = 0; ks < 2; ++ks) {
    const int cu = ks * 32 + lhi * 8;
    bf16x8 a[4];
#pragma unroll
    for (int nf = 0; nf < 4; ++nf) {
      int rn = w * 64 + nf * 16 + l16;
      a[nf] = *(const bf16x8*)&sO[rn * 64 + (cu ^ ((rn & 7) * 8))];
    }
#pragma unroll
    for (int cf = 0; cf < 4; ++cf) {
      int rw = cf * 16 + l16;
      bf16x8 bb = *(const bf16x8*)&sWo[rw * 64 + (cu ^ ((rw & 7) * 8))];
#pragma unroll
      for (int nf = 0; nf < 4; ++nf)
        acc[nf][cf] = __builtin_amdgcn_mfma_f32_16x16x32_bf16(a[nf], bb, acc[nf][cf], 0, 0, 0);
    }
  }

#pragma unroll
  for (int nf = 0; nf < 4; ++nf) {
    const int n = nt * 256 + w * 64 + nf * 16 + lhi * 4;
#pragma unroll
    for (int cf = 0; cf < 4; ++cf) {
      const int co = ct * 64 + cf * 16 + l16;
      const size_t off = ((size_t)b * CHN + co) * NPOS + n;
      f32x4 rr;
      rr[0] = fmaf(gv, acc[nf][cf][0], xv[nf][cf].x);
      rr[1] = fmaf(gv, acc[nf][cf][1], xv[nf][cf].y);
      rr[2] = fmaf(gv, acc[nf][cf][2], xv[nf][cf].z);
      rr[3] = fmaf(gv, acc[nf][cf][3], xv[nf][cf].w);
      __builtin_nontemporal_store(rr, (f32x4*)(outp + off));
    }
  }
}

// ---------------------------------------------------------------------------
extern "C" void kernel_launch(void* const* d_in, const int* in_sizes, int n_in,
                              void* d_out, int out_size, void* d_ws, size_t ws_size,
                              hipStream_t stream)
{
  const float* x     = (const float*)d_in[0];
  const float* Wt    = (const float*)d_in[1];
  const float* Wp    = (const float*)d_in[2];
  const float* Wg    = (const float*)d_in[3];
  const float* Wo    = (const float*)d_in[4];
  const float* gamma = (const float*)d_in[5];
  float* out = (float*)d_out;
  float* ws  = (float*)d_ws;

  unsigned short* obf = (unsigned short*)(ws + OFF_O);
  unsigned short* thT = (unsigned short*)(ws + OFF_THT);
  unsigned short* phT = (unsigned short*)(ws + OFF_PHT);
  unsigned short* gbf = (unsigned short*)(ws + OFF_GB);
  unsigned short* wbf = (unsigned short*)(ws + OFF_WBF);
  unsigned short* wob = (unsigned short*)(ws + OFF_WOB);

  prep_w_kernel<<<dim3(512), 256, 0, stream>>>(Wt, Wp, Wg, Wo, wbf, wob);
  qkv_fused_kernel<<<dim3(32, 16), 256, 0, stream>>>(x, wbf, thT, phT, gbf);
  attn_kernel<<<dim3(32, 16), 256, 0, stream>>>(thT, phT, gbf, obf);
  outconv_mfma_kernel<<<dim3(16, 8, 16), 256, 0, stream>>>(x, wob, obf, gamma, out);
}

// Round 15
// 120.798 us; speedup vs baseline: 1.0334x; 1.0068x over previous
//
#include <hip/hip_runtime.h>

#define CHN 512
#define CKD 64
#define NPOS 4096
#define MPOS 1024

typedef __attribute__((ext_vector_type(8))) short bf16x8;
typedef __attribute__((ext_vector_type(4))) float f32x4;
typedef __attribute__((ext_vector_type(8))) unsigned short u16x8;

// workspace offsets (float units)
static constexpr size_t OFF_O   = 0;          // bf16 o [16][4096][64] (n-major, ck-minor)
static constexpr size_t OFF_THT = 4194304;    // bf16 thetaT [16][4096][64]
static constexpr size_t OFF_PHT = 6291456;    // bf16 phiT   [16][1024][64]
static constexpr size_t OFF_GB  = 6815744;    // bf16 g      [16][64][1024]
static constexpr size_t OFF_WBF = 7340032;    // bf16 W[3][64][512] (k-minor, natural)
static constexpr size_t OFF_WOB = 7389184;    // bf16 Wo [512][64] (k-minor, natural)

__device__ __forceinline__ unsigned short f2bf(float f) {
  union { float f; unsigned int u; } v; v.f = f;
  unsigned int r = v.u + 0x7FFFu + ((v.u >> 16) & 1u);
  return (unsigned short)(r >> 16);
}

__device__ __forceinline__ void gl2lds16(const void* g, void* l) {
  __builtin_amdgcn_global_load_lds(
      (const __attribute__((address_space(1))) unsigned int*)g,
      (__attribute__((address_space(3))) unsigned int*)l, 16, 0, 0);
}

// ---------------------------------------------------------------------------
// K0: weight prep. (unchanged)
// ---------------------------------------------------------------------------
__global__ __launch_bounds__(256) void prep_w_kernel(
    const float* __restrict__ Wt, const float* __restrict__ Wp,
    const float* __restrict__ Wg, const float* __restrict__ Wo,
    unsigned short* __restrict__ wbf, unsigned short* __restrict__ wobf)
{
  int id = blockIdx.x * 256 + threadIdx.x;   // 0..131071
  if (id < 98304) {
    int mat = id >> 15, r = id & 32767;
    const float* W = (mat == 0) ? Wt : (mat == 1) ? Wp : Wg;
    wbf[id] = f2bf(W[r]);
  } else {
    int j = id - 98304;                      // 0..32767
    wobf[j] = f2bf(Wo[j]);
  }
}

// ---------------------------------------------------------------------------
// K1: FUSED transpose + qkv GEMM via MFMA, reg-staged x (2-deep) and W.
// (unchanged from round 14)
// ---------------------------------------------------------------------------
__global__ __launch_bounds__(256) void qkv_fused_kernel(
    const float* __restrict__ x,             // [b][512][4096] fp32
    const unsigned short* __restrict__ wbf,  // [3][64][512]
    unsigned short* __restrict__ thT, unsigned short* __restrict__ phT,
    unsigned short* __restrict__ gbf)
{
  __shared__ unsigned short sXb[64 * 132];   // [c][n] bf16, +4 pad
  __shared__ unsigned short sW[3 * 64 * 64]; // [mat][ck][c] rows 128B, swizzled

  const int bx = blockIdx.x;
  const int b  = blockIdx.y;
  const int t  = threadIdx.x;
  const int w   = t >> 6;
  const int l   = t & 63;
  const int l16 = l & 15;
  const int lhi = l >> 4;
  const int n0  = bx * 128;

  const float* xb = x + (size_t)b * CHN * NPOS + n0;
  const int xrow = t >> 5;                   // 0..7 base row
  const int xcol4 = t & 31;

  f32x4 acc[3][2][4];
#pragma unroll
  for (int m = 0; m < 3; ++m)
#pragma unroll
    for (int nf = 0; nf < 2; ++nf)
#pragma unroll
      for (int ckf = 0; ckf < 4; ++ckf) acc[m][nf][ckf] = (f32x4){0.f, 0.f, 0.f, 0.f};

#define LOADX(buf, c0)                                                         \
  _Pragma("unroll")                                                            \
  for (int i = 0; i < 8; ++i)                                                  \
    buf[i] = *(const float4*)(xb + (size_t)((c0) + i * 8 + xrow) * NPOS + xcol4 * 4);

#define WRITEX(buf)                                                            \
  _Pragma("unroll")                                                            \
  for (int i = 0; i < 8; ++i) {                                                \
    ushort4 u;                                                                 \
    u.x = f2bf(buf[i].x); u.y = f2bf(buf[i].y);                                \
    u.z = f2bf(buf[i].z); u.w = f2bf(buf[i].w);                                \
    *(ushort4*)&sXb[(i * 8 + xrow) * 132 + xcol4 * 4] = u;                     \
  }

#define LOADW(wR, c0)                                                          \
  _Pragma("unroll")                                                            \
  for (int mi = 0; mi < 6; ++mi) {                                             \
    int row = ((mi & 1) * 4 + w) * 8 + (l >> 3);                               \
    int sbyte = (l & 7) * 16;                                                  \
    int mat = mi >> 1;                                                         \
    wR[mi] = *(const u16x8*)((const char*)wbf +                                \
        ((((size_t)mat * 64 + row) * CHN + (c0)) << 1) + (sbyte ^ ((row & 7) << 4))); \
  }

#define WRITEW(wR)                                                             \
  _Pragma("unroll")                                                            \
  for (int mi = 0; mi < 6; ++mi)                                               \
    *(u16x8*)((char*)sW + mi * 4096 + w * 1024 + l * 16) = wR[mi];

#define MFMA_PHASE()                                                           \
  _Pragma("unroll")                                                            \
  for (int ks = 0; ks < 2; ++ks) {                                             \
    const int cu = ks * 32 + lhi * 8;                                          \
    bf16x8 a[2];                                                               \
    _Pragma("unroll")                                                          \
    for (int nf = 0; nf < 2; ++nf) {                                           \
      const int rn = 16 * w + 64 * nf + l16;                                   \
      bf16x8 av;                                                               \
      _Pragma("unroll")                                                        \
      for (int e = 0; e < 8; ++e)                                              \
        av[e] = (short)sXb[(cu + e) * 132 + rn];                               \
      a[nf] = av;                                                              \
    }                                                                          \
    _Pragma("unroll")                                                          \
    for (int m = 0; m < 3; ++m)                                                \
      _Pragma("unroll")                                                        \
      for (int ckf = 0; ckf < 4; ++ckf) {                                      \
        int rw = ckf * 16 + l16;                                               \
        bf16x8 bb = *(const bf16x8*)&sW[m * 4096 + rw * 64 + (cu ^ ((rw & 7) * 8))]; \
        acc[m][0][ckf] = __builtin_amdgcn_mfma_f32_16x16x32_bf16(a[0], bb, acc[m][0][ckf], 0, 0, 0); \
        acc[m][1][ckf] = __builtin_amdgcn_mfma_f32_16x16x32_bf16(a[1], bb, acc[m][1][ckf], 0, 0, 0); \
      }                                                                        \
  }

  // prologue: x 2-deep, W 1-deep
  float4 xA[8], xB[8];
  u16x8 wR[6];
  LOADX(xA, 0);
  LOADX(xB, 64);
  LOADW(wR, 0);

#pragma unroll
  for (int cc = 0; cc < 4; ++cc) {
    const int c0 = cc * 128;
    if (c0) __syncthreads();
    WRITEX(xA);
    WRITEW(wR);
    __syncthreads();
    if (c0 + 128 < CHN) LOADX(xA, c0 + 128);
    LOADW(wR, c0 + 64);
    MFMA_PHASE();

    __syncthreads();
    WRITEX(xB);
    WRITEW(wR);
    __syncthreads();
    if (c0 + 192 < CHN) LOADX(xB, c0 + 192);
    if (c0 + 128 < CHN) LOADW(wR, c0 + 128);
    MFMA_PHASE();
  }

#undef LOADX
#undef WRITEX
#undef LOADW
#undef WRITEW
#undef MFMA_PHASE

  // epilogue: theta full-res [n][ck] bf16
  unsigned short* th = thT + (size_t)b * NPOS * 64;
#pragma unroll
  for (int nf = 0; nf < 2; ++nf)
#pragma unroll
    for (int r = 0; r < 4; ++r) {
      int n = n0 + 16 * w + 64 * nf + lhi * 4 + r;
#pragma unroll
      for (int ckf = 0; ckf < 4; ++ckf)
        th[(size_t)n * 64 + ckf * 16 + l16] = f2bf(acc[0][nf][ckf][r]);
    }

  // phi/g: 2x2 maxpool in-register.
  unsigned short* ph = phT + (size_t)b * MPOS * 64;
  unsigned short* gb = gbf + (size_t)b * CKD * MPOS;
#pragma unroll
  for (int pr = 0; pr < 2; ++pr) {
    int mcol = bx * 32 + 8 * w + lhi * 2 + pr;
#pragma unroll
    for (int ckf = 0; ckf < 4; ++ckf) {
      int ck = ckf * 16 + l16;
      float vp = fmaxf(fmaxf(acc[1][0][ckf][2 * pr], acc[1][0][ckf][2 * pr + 1]),
                       fmaxf(acc[1][1][ckf][2 * pr], acc[1][1][ckf][2 * pr + 1]));
      float vg = fmaxf(fmaxf(acc[2][0][ckf][2 * pr], acc[2][0][ckf][2 * pr + 1]),
                       fmaxf(acc[2][1][ckf][2 * pr], acc[2][1][ckf][2 * pr + 1]));
      ph[(size_t)mcol * 64 + ck] = f2bf(vp);
      gb[(size_t)ck * MPOS + mcol] = f2bf(vg);
    }
  }
}

// ---------------------------------------------------------------------------
// K2: fused flash attention, QBLK=64 (occupancy probe: 32 KB LDS, 1024
// blocks = 4/CU, 16 waves/CU vs r14's 8). Keeps no-max softmax, ones-MFMA
// row-sum, T14 reg-staged phi/g. grid (64 q-tiles of 64, 16 b), 4 waves.
// ---------------------------------------------------------------------------
__global__ __launch_bounds__(256) void attn_kernel(
    const unsigned short* __restrict__ thT,  // [b][4096][64]
    const unsigned short* __restrict__ phT,  // [b][1024][64]
    const unsigned short* __restrict__ gbf,  // [b][64][1024]
    unsigned short* __restrict__ obf)        // [b][4096][64] bf16
{
  __shared__ unsigned short sTh[64 * 64];    // [q][ck] swizzled rows 128B
  __shared__ unsigned short sP [64 * 64];    // [q][m]  swizzled
  __shared__ unsigned short sPhi[64 * 64];   // [m][ck] swizzled
  __shared__ unsigned short sG [64 * 64];    // [ck][m] swizzled

  const int qt = blockIdx.x;                 // 64 tiles of 64 q
  const int b  = blockIdx.y;
  const int t  = threadIdx.x;
  const int w   = t >> 6;
  const int l   = t & 63;
  const int l16 = l & 15;
  const int lhi = l >> 4;

  // stage theta tile: 64 rows x 128B = 512 chunks (async; drains at barrier)
  {
    const char* srcb = (const char*)(thT + ((size_t)b * NPOS + (size_t)qt * 64) * 64);
#pragma unroll
    for (int i = 0; i < 2; ++i) {
      int cidx = i * 256 + t;
      int row = cidx >> 3, sub = cidx & 7;
      gl2lds16(srcb + row * 128 + ((sub * 16) ^ ((row & 7) << 4)),
               (char*)sTh + (i * 256 + w * 64) * 16);
    }
  }

  f32x4 oacc[4];
  f32x4 lacc;                                // row-sum accumulator (ones-MFMA)
  lacc = (f32x4){0.f, 0.f, 0.f, 0.f};
#pragma unroll
  for (int i = 0; i < 4; ++i) oacc[i] = (f32x4){0.f, 0.f, 0.f, 0.f};

  bf16x8 ones;
#pragma unroll
  for (int e = 0; e < 8; ++e) ones[e] = (short)0x3F80;   // bf16 1.0

  const unsigned short* phb = phT + (size_t)b * MPOS * 64;
  const unsigned short* gb  = gbf + (size_t)b * CKD * MPOS;

  // T14 prologue: prefetch phi/g tiles for mt=0 into registers
  const int srow = t >> 3;                   // 0..31 base row (i adds 32)
  const int ssub = t & 7;
  u16x8 phR[2], gR[2];
#pragma unroll
  for (int i = 0; i < 2; ++i) {
    int row = i * 32 + srow;
    phR[i] = *(const u16x8*)(phb + (size_t)row * 64 + ssub * 8);
    gR[i]  = *(const u16x8*)(gb + (size_t)row * MPOS + ssub * 8);
  }

  for (int mt = 0; mt < 16; ++mt) {
    __syncthreads();                         // prev-iter readers done (+theta drain at mt=0)
#pragma unroll
    for (int i = 0; i < 2; ++i) {
      int row = i * 32 + srow;
      int off = row * 64 + ((ssub * 8) ^ ((row & 7) * 8));
      *(u16x8*)&sPhi[off] = phR[i];
      *(u16x8*)&sG[off]   = gR[i];
    }
    __syncthreads();                         // writes visible

    if (mt + 1 < 16) {
#pragma unroll
      for (int i = 0; i < 2; ++i) {
        int row = i * 32 + srow;
        phR[i] = *(const u16x8*)(phb + (size_t)((mt + 1) * 64 + row) * 64 + ssub * 8);
        gR[i]  = *(const u16x8*)(gb + (size_t)row * MPOS + (mt + 1) * 64 + ssub * 8);
      }
    }

    // QK^T: S[16q x 64m] per wave
    f32x4 sacc[4];
#pragma unroll
    for (int mf = 0; mf < 4; ++mf) sacc[mf] = (f32x4){0.f, 0.f, 0.f, 0.f};
#pragma unroll
    for (int ks = 0; ks < 2; ++ks) {
      const int q  = 16 * w + l16;
      const int ob = lhi * 8 + 32 * ks;
      bf16x8 a = *(const bf16x8*)&sTh[q * 64 + (ob ^ ((q & 7) * 8))];
#pragma unroll
      for (int mf = 0; mf < 4; ++mf) {
        const int m = l16 + 16 * mf;
        bf16x8 bb = *(const bf16x8*)&sPhi[m * 64 + (ob ^ ((m & 7) * 8))];
        sacc[mf] = __builtin_amdgcn_mfma_f32_16x16x32_bf16(a, bb, sacc[mf], 0, 0, 0);
      }
    }

    // softmax numerator: p = expf(s) (no max subtraction), write P to LDS
#pragma unroll
    for (int r = 0; r < 4; ++r) {
      const int qq = 16 * w + lhi * 4 + r;
      const int swz = (qq & 7) * 8;
#pragma unroll
      for (int mf = 0; mf < 4; ++mf) {
        const int m = l16 + 16 * mf;
        sP[qq * 64 + ((m & 0x38) ^ swz) + (m & 7)] = f2bf(__expf(sacc[mf][r]));
      }
    }

    // PV: O += P * g^T; row-sum l += P * 1 (ones-MFMA, same A-frags)
#pragma unroll
    for (int ks = 0; ks < 2; ++ks) {
      const int q  = 16 * w + l16;
      const int ob = lhi * 8 + 32 * ks;
      bf16x8 a = *(const bf16x8*)&sP[q * 64 + (ob ^ ((q & 7) * 8))];
      lacc = __builtin_amdgcn_mfma_f32_16x16x32_bf16(a, ones, lacc, 0, 0, 0);
#pragma unroll
      for (int ckf = 0; ckf < 4; ++ckf) {
        const int ck = l16 + 16 * ckf;
        bf16x8 bb = *(const bf16x8*)&sG[ck * 64 + (ob ^ ((ck & 7) * 8))];
        oacc[ckf] = __builtin_amdgcn_mfma_f32_16x16x32_bf16(a, bb, oacc[ckf], 0, 0, 0);
      }
    }
  }

  // epilogue: normalize, write o bf16 [n][ck]
  unsigned short* ob = obf + (size_t)b * NPOS * 64;
  float inv[4];
#pragma unroll
  for (int r = 0; r < 4; ++r) inv[r] = 1.0f / lacc[r];
#pragma unroll
  for (int r = 0; r < 4; ++r) {
    int n = qt * 64 + 16 * w + lhi * 4 + r;
#pragma unroll
    for (int ckf = 0; ckf < 4; ++ckf)
      ob[(size_t)n * 64 + ckf * 16 + l16] = f2bf(oacc[ckf][r] * inv[r]);
  }
}

// ---------------------------------------------------------------------------
// K3: out = x + gamma * (Wo @ o) via bf16 MFMA. (unchanged from round 13)
// ---------------------------------------------------------------------------
__global__ __launch_bounds__(256) void outconv_mfma_kernel(
    const float* __restrict__ x,
    const unsigned short* __restrict__ wobf,  // [512][64] bf16 k-minor
    const unsigned short* __restrict__ obf,   // [b][4096][64] bf16
    const float* __restrict__ gamma_p, float* __restrict__ outp)
{
  __shared__ unsigned short sO[256 * 64];     // [n][ck] rows 128B, swizzled
  __shared__ unsigned short sWo[64 * 64];     // [co][ck] rows 128B, swizzled

  const int nt = blockIdx.x;                  // 16 tiles of 256 n
  const int ct = blockIdx.y;                  // 8 tiles of 64 co
  const int b  = blockIdx.z;
  const int t  = threadIdx.x;
  const int w   = t >> 6;
  const int l   = t & 63;
  const int l16 = l & 15;
  const int lhi = l >> 4;

#pragma unroll
  for (int i = 0; i < 8; ++i) {
    int cidx = i * 256 + t;
    int row = cidx >> 3, sub = cidx & 7;
    const char* g = (const char*)obf +
        ((((size_t)b * NPOS + nt * 256 + row) * 64) << 1) + ((sub * 16) ^ ((row & 7) << 4));
    gl2lds16(g, (char*)sO + (i * 256 + w * 64) * 16);
  }
#pragma unroll
  for (int i = 0; i < 2; ++i) {
    int cidx = i * 256 + t;
    int row = cidx >> 3, sub = cidx & 7;      // row 0..63
    const char* g = (const char*)wobf +
        ((((size_t)(ct * 64 + row)) * 64) << 1) + ((sub * 16) ^ ((row & 7) << 4));
    gl2lds16(g, (char*)sWo + (i * 256 + w * 64) * 16);
  }

  const float gv = *gamma_p;
  float4 xv[4][4];
#pragma unroll
  for (int nf = 0; nf < 4; ++nf) {
    const int n = nt * 256 + w * 64 + nf * 16 + lhi * 4;
#pragma unroll
    for (int cf = 0; cf < 4; ++cf) {
      const int co = ct * 64 + cf * 16 + l16;
      xv[nf][cf] = *(const float4*)(x + ((size_t)b * CHN + co) * NPOS + n);
    }
  }
  __syncthreads();

  f32x4 acc[4][4];
#pragma unroll
  for (int nf = 0; nf < 4; ++nf)
#pragma unroll
    for (int cf = 0; cf < 4; ++cf) acc[nf][cf] = (f32x4){0.f, 0.f, 0.f, 0.f};

#pragma unroll
  for (int ks = 0; ks < 2; ++ks) {
    const int cu = ks * 32 + lhi * 8;
    bf16x8 a[4];
#pragma unroll
    for (int nf = 0; nf < 4; ++nf) {
      int rn = w * 64 + nf * 16 + l16;
      a[nf] = *(const bf16x8*)&sO[rn * 64 + (cu ^ ((rn & 7) * 8))];
    }
#pragma unroll
    for (int cf = 0; cf < 4; ++cf) {
      int rw = cf * 16 + l16;
      bf16x8 bb = *(const bf16x8*)&sWo[rw * 64 + (cu ^ ((rw & 7) * 8))];
#pragma unroll
      for (int nf = 0; nf < 4; ++nf)
        acc[nf][cf] = __builtin_amdgcn_mfma_f32_16x16x32_bf16(a[nf], bb, acc[nf][cf], 0, 0, 0);
    }
  }

#pragma unroll
  for (int nf = 0; nf < 4; ++nf) {
    const int n = nt * 256 + w * 64 + nf * 16 + lhi * 4;
#pragma unroll
    for (int cf = 0; cf < 4; ++cf) {
      const int co = ct * 64 + cf * 16 + l16;
      const size_t off = ((size_t)b * CHN + co) * NPOS + n;
      f32x4 rr;
      rr[0] = fmaf(gv, acc[nf][cf][0], xv[nf][cf].x);
      rr[1] = fmaf(gv, acc[nf][cf][1], xv[nf][cf].y);
      rr[2] = fmaf(gv, acc[nf][cf][2], xv[nf][cf].z);
      rr[3] = fmaf(gv, acc[nf][cf][3], xv[nf][cf].w);
      __builtin_nontemporal_store(rr, (f32x4*)(outp + off));
    }
  }
}

// ---------------------------------------------------------------------------
extern "C" void kernel_launch(void* const* d_in, const int* in_sizes, int n_in,
                              void* d_out, int out_size, void* d_ws, size_t ws_size,
                              hipStream_t stream)
{
  const float* x     = (const float*)d_in[0];
  const float* Wt    = (const float*)d_in[1];
  const float* Wp    = (const float*)d_in[2];
  const float* Wg    = (const float*)d_in[3];
  const float* Wo    = (const float*)d_in[4];
  const float* gamma = (const float*)d_in[5];
  float* out = (float*)d_out;
  float* ws  = (float*)d_ws;

  unsigned short* obf = (unsigned short*)(ws + OFF_O);
  unsigned short* thT = (unsigned short*)(ws + OFF_THT);
  unsigned short* phT = (unsigned short*)(ws + OFF_PHT);
  unsigned short* gbf = (unsigned short*)(ws + OFF_GB);
  unsigned short* wbf = (unsigned short*)(ws + OFF_WBF);
  unsigned short* wob = (unsigned short*)(ws + OFF_WOB);

  prep_w_kernel<<<dim3(512), 256, 0, stream>>>(Wt, Wp, Wg, Wo, wbf, wob);
  qkv_fused_kernel<<<dim3(32, 16), 256, 0, stream>>>(x, wbf, thT, phT, gbf);
  attn_kernel<<<dim3(64, 16), 256, 0, stream>>>(thT, phT, gbf, obf);
  outconv_mfma_kernel<<<dim3(16, 8, 16), 256, 0, stream>>>(x, wob, obf, gamma, out);
}